// Round 8
// baseline (955.354 us; speedup 1.0000x reference)
//
#include <hip/hip_runtime.h>
#include <hip/hip_bf16.h>

// RNN scan via MFMA. T=750 serial steps; per step the batched update
//   x = 0.9x + 0.1*( r @ J^T + u @ b_in^T + c_x + 0.1*n ),  r = tanh(x)
// is a [1024,100]x[100,100] GEMM -> mfma_f32_16x16x32_bf16 with hi/lo bf16
// decomposition of BOTH operands (3 products, f32-grade accuracy).
// Block = 16 batches x 7 waves; wave n owns h-tile [16n,16n+16).
// J held as B-fragments in 32 pinned VGPRs/lane. r exchanged per step via
// LDS (hi/lo planes, padded stride), 8 ds_read_b128 per wave per step.

typedef __attribute__((ext_vector_type(8))) short bf16x8;
typedef __attribute__((ext_vector_type(4))) float f32x4;

#define TSTEPS 750
#define BATCH  1024
#define HID    100
#define NT     7        // 7 h-tiles of 16 -> N=112 (cols 100..111 zero)
#define KT     4        // 4 k-tiles of 32 -> K=128 (k 100..127 zero)
#define KSTRIDE 136     // LDS row stride in bf16 elems: 272B, 16B-aligned, bank-spread
#define THREADS (NT * 64)

constexpr float ALPHA = 0.1f;   // DT/TAU
constexpr float NSTD  = 0.1f;

__device__ __forceinline__ float ftanh(float x) {
    float e = __expf(2.0f * x);
    return 1.0f - 2.0f * __builtin_amdgcn_rcpf(e + 1.0f);
}

// round-to-nearest bf16 hi/lo split: v ~= hi + lo, |v-hi-lo| <~ 2^-16 |v|
__device__ __forceinline__ void bsplit(float v, unsigned& hi, unsigned& lo) {
    __hip_bfloat16 h = __float2bfloat16(v);
    unsigned hb = *reinterpret_cast<unsigned short*>(&h);
    float hf = __builtin_bit_cast(float, hb << 16);
    __hip_bfloat16 l = __float2bfloat16(v - hf);
    hi = hb;
    lo = *reinterpret_cast<unsigned short*>(&l);
}

__global__ void __launch_bounds__(THREADS)
__attribute__((amdgpu_waves_per_eu(1, 2)))
rnn_mfma_kernel(const float* __restrict__ input_seq,  // [T,B,4]
                const float* __restrict__ noise,      // [T,B,H]
                const float* __restrict__ J_w,        // [H,H]
                const float* __restrict__ b_in,       // [H,4]
                const float* __restrict__ c_x,        // [H]
                float* __restrict__ states)           // [T,B,H]
{
    const int tid = threadIdx.x;
    const int w   = tid >> 6;        // wave id = N-tile
    const int l   = tid & 63;
    const int lr  = l & 15;          // lane row-in-group: h-col for B/C, batch-row for A
    const int lg  = l >> 4;          // lane group 0..3
    const int bid = blockIdx.x;      // batch tile (16 batches)

    const int  h    = w * 16 + lr;   // this lane's output h column
    const bool hval = (h < HID);
    const int  hc   = hval ? h : (HID - 1);

    __shared__ __align__(16) unsigned short rHI[2][16][KSTRIDE];
    __shared__ __align__(16) unsigned short rLO[2][16][KSTRIDE];

    // zero-init both buffers (r(x0)=tanh(0)=0; k>=100 stays 0 forever)
    for (int i = tid; i < 2 * 16 * KSTRIDE; i += THREADS) {
        (&rHI[0][0][0])[i] = 0;
        (&rLO[0][0][0])[i] = 0;
    }

    // ---- Build J B-fragments (static): tile t, lane: col h, k = 32t + 8*lg + j ----
    // B-frag assumption (CDNA4 16x16x32): col = lane&15, k = (lane>>4)*8 + j, j contiguous.
    int4 BH[KT], BL[KT];   // hi/lo planes, 16B each = 4 VGPRs
#pragma unroll
    for (int t = 0; t < KT; ++t) {
        unsigned hs[8], ls[8];
#pragma unroll
        for (int j = 0; j < 8; ++j) {
            int k = 32 * t + 8 * lg + j;
            float v = (hval && k < HID) ? J_w[(size_t)hc * HID + k] : 0.0f;
            bsplit(v, hs[j], ls[j]);
        }
        BH[t] = make_int4((int)(hs[0] | (hs[1] << 16)), (int)(hs[2] | (hs[3] << 16)),
                          (int)(hs[4] | (hs[5] << 16)), (int)(hs[6] | (hs[7] << 16)));
        BL[t] = make_int4((int)(ls[0] | (ls[1] << 16)), (int)(ls[2] | (ls[3] << 16)),
                          (int)(ls[4] | (ls[5] << 16)), (int)(ls[6] | (ls[7] << 16)));
    }
    // Pin (scalar components, R6-style): prevents remat/sink of the J frags.
#define PINV(q) asm volatile("" : "+v"(q.x), "+v"(q.y), "+v"(q.z), "+v"(q.w));
    PINV(BH[0]) PINV(BH[1]) PINV(BH[2]) PINV(BH[3])
    PINV(BL[0]) PINV(BL[1]) PINV(BL[2]) PINV(BL[3])
#undef PINV

    const float4 binp = *reinterpret_cast<const float4*>(b_in + (size_t)hc * 4);
    const float  cx   = c_x[hc];

    // x state: 4 batch rows m = 4*lg + i  (C layout: row=(lane>>4)*4+reg, col=lane&15)
    float x0 = 0.f, x1 = 0.f, x2 = 0.f, x3 = 0.f;

    const size_t bbase = (size_t)bid * 16;

    __syncthreads();   // LDS init visible to all

    for (int t = 0; t < TSTEPS; ++t) {
        const int cur = t & 1, nxt = cur ^ 1;

        // ---- per-step inputs (issued first: longest latency) ----
        float nz[4], ud[4];
#pragma unroll
        for (int i = 0; i < 4; ++i) {
            const size_t b_i = bbase + 4 * lg + i;
            nz[i] = noise[((size_t)t * BATCH + b_i) * HID + hc];
            float4 uu = *reinterpret_cast<const float4*>(input_seq + ((size_t)t * BATCH + b_i) * 4);
            ud[i] = uu.x * binp.x + uu.y * binp.y + uu.z * binp.z + uu.w * binp.w;
        }

        // ---- A-fragments of r (hi/lo) from LDS ----
        // A layout assumption: row = lane&15 (batch), k = (lane>>4)*8 + j contiguous.
        f32x4 aA = {0.f, 0.f, 0.f, 0.f}, aB = aA, aC = aA;
#pragma unroll
        for (int kt = 0; kt < KT; ++kt) {
            const int eoff = (4 * kt + lg) * 8;   // element offset in row
            bf16x8 ah = *reinterpret_cast<const bf16x8*>(&rHI[cur][lr][eoff]);
            bf16x8 al = *reinterpret_cast<const bf16x8*>(&rLO[cur][lr][eoff]);
            bf16x8 jh = __builtin_bit_cast(bf16x8, BH[kt]);
            bf16x8 jl = __builtin_bit_cast(bf16x8, BL[kt]);
            aA = __builtin_amdgcn_mfma_f32_16x16x32_bf16(ah, jh, aA, 0, 0, 0);
            aB = __builtin_amdgcn_mfma_f32_16x16x32_bf16(al, jh, aB, 0, 0, 0);
            aC = __builtin_amdgcn_mfma_f32_16x16x32_bf16(ah, jl, aC, 0, 0, 0);
        }
        f32x4 dot = (aA + aB) + aC;

        // ---- state update + store + pack r_{t+1} ----
        float xs[4] = {x0, x1, x2, x3};
#pragma unroll
        for (int i = 0; i < 4; ++i) {
            float pre = dot[i] + ud[i] + cx + NSTD * nz[i];
            float xn = xs[i] + ALPHA * (pre - xs[i]);
            xs[i] = xn;
            const size_t b_i = bbase + 4 * lg + i;
            if (hval) {
                states[((size_t)t * BATCH + b_i) * HID + h] = xn;
                unsigned rh, rl;
                bsplit(ftanh(xn), rh, rl);
                const int m = 4 * lg + i;
                rHI[nxt][m][h] = (unsigned short)rh;
                rLO[nxt][m][h] = (unsigned short)rl;
            }
        }
        x0 = xs[0]; x1 = xs[1]; x2 = xs[2]; x3 = xs[3];

        // Raw barrier: drain LDS ops only (global stores stay in flight).
        asm volatile("s_waitcnt lgkmcnt(0)" ::: "memory");
        __builtin_amdgcn_s_barrier();
        __builtin_amdgcn_sched_barrier(0);
    }
}

// Readout: out[b,0] = tanh(states[0,b,:]).wout + wb ; out[b,1] = same at T-1.
__global__ __launch_bounds__(64) void rnn_out_kernel(
    const float* __restrict__ states,
    const float* __restrict__ wout_w,
    const float* __restrict__ wout_b,
    float* __restrict__ out)
{
    const int b = blockIdx.x;
    const int l = threadIdx.x;
    const float* s0 = states + (size_t)b * HID;
    const float* sF = states + ((size_t)(TSTEPS - 1) * BATCH + b) * HID;

    float p0 = 0.f, pF = 0.f;
    if (l < HID) {
        p0 = ftanh(s0[l]) * wout_w[l];
        pF = ftanh(sF[l]) * wout_w[l];
    }
    const int l2 = l + 64;
    if (l2 < HID) {
        p0 += ftanh(s0[l2]) * wout_w[l2];
        pF += ftanh(sF[l2]) * wout_w[l2];
    }
#pragma unroll
    for (int off = 32; off > 0; off >>= 1) {
        p0 += __shfl_xor(p0, off, 64);
        pF += __shfl_xor(pF, off, 64);
    }
    if (l == 0) {
        const float wb = wout_b[0];
        out[b * 2 + 0] = p0 + wb;
        out[b * 2 + 1] = pF + wb;
    }
}

extern "C" void kernel_launch(void* const* d_in, const int* in_sizes, int n_in,
                              void* d_out, int out_size, void* d_ws, size_t ws_size,
                              hipStream_t stream) {
    const float* input_seq = (const float*)d_in[0];
    const float* noise     = (const float*)d_in[1];
    const float* J_w       = (const float*)d_in[2];
    const float* b_in      = (const float*)d_in[3];
    const float* c_x       = (const float*)d_in[4];
    const float* wout_w    = (const float*)d_in[5];
    const float* wout_b    = (const float*)d_in[6];

    float* out    = (float*)d_out;       // [B,2]
    float* states = out + 2 * BATCH;     // [T,B,H]

    rnn_mfma_kernel<<<BATCH / 16, THREADS, 0, stream>>>(
        input_seq, noise, J_w, b_in, c_x, states);
    rnn_out_kernel<<<BATCH, 64, 0, stream>>>(states, wout_w, wout_b, out);
}

// Round 9
// 737.750 us; speedup vs baseline: 1.2950x; 1.2950x over previous
//
#include <hip/hip_runtime.h>
#include <hip/hip_bf16.h>

// RNN scan via MFMA, latency-optimized. T=750 serial steps; per step
//   x = x + ALPHA*(-x + r@J^T + u@b_in^T + c_x + 0.1*n),  r = tanh(x)
// Block = 16 batches x 7 waves (wave w owns h-tile [16w,16w+16)), 64 blocks.
// J as static B-fragments in pinned VGPRs, hi/lo bf16 (J error ~0).
// r exchanged per step via LDS in SINGLE bf16 (error ~2e-3 << 0.043 thr).
// Inputs (noise,u) prefetched 2 steps ahead in registers; the raw
// s_barrier+lgkmcnt(0) (no vmcnt drain) keeps those loads in flight.

typedef __attribute__((ext_vector_type(8))) short bf16x8;
typedef __attribute__((ext_vector_type(4))) float f32x4;

#define TSTEPS 750
#define BATCH  1024
#define HID    100
#define NT     7        // 7 h-tiles of 16 -> N=112 (cols 100..111 zero)
#define KT     4        // 4 k-tiles of 32 -> K=128 (k 100..127 zero)
#define KSTRIDE 136     // LDS row stride in bf16: 272B = 17*16B -> b128 reads even over banks
#define THREADS (NT * 64)

constexpr float ALPHA = 0.1f;   // DT/TAU
constexpr float NSTD  = 0.1f;

__device__ __forceinline__ float ftanh(float x) {
    float e = __expf(2.0f * x);
    return 1.0f - 2.0f * __builtin_amdgcn_rcpf(e + 1.0f);
}

// round-to-nearest bf16 hi/lo split: v ~= hi + lo
__device__ __forceinline__ void bsplit(float v, unsigned& hi, unsigned& lo) {
    __hip_bfloat16 h = __float2bfloat16(v);
    unsigned hb = *reinterpret_cast<unsigned short*>(&h);
    float hf = __builtin_bit_cast(float, hb << 16);
    __hip_bfloat16 l = __float2bfloat16(v - hf);
    hi = hb;
    lo = *reinterpret_cast<unsigned short*>(&l);
}

__global__ void __launch_bounds__(THREADS)
rnn_mfma_kernel(const float* __restrict__ input_seq,  // [T,B,4]
                const float* __restrict__ noise,      // [T,B,H]
                const float* __restrict__ J_w,        // [H,H]
                const float* __restrict__ b_in,       // [H,4]
                const float* __restrict__ c_x,        // [H]
                float* __restrict__ states)           // [T,B,H]
{
    const int tid = threadIdx.x;
    const int w   = tid >> 6;        // wave id = N-tile
    const int l   = tid & 63;
    const int lr  = l & 15;          // B/C col within tile; A batch-row
    const int lg  = l >> 4;          // lane group 0..3
    const int bid = blockIdx.x;      // batch tile (16 batches)

    const int  h    = w * 16 + lr;   // this lane's output h column
    const bool hval = (h < HID);
    const int  hc   = hval ? h : (HID - 1);

    // single bf16 r plane, double-buffered
    __shared__ __align__(16) unsigned short rB[2][16][KSTRIDE];
    for (int i = tid; i < 2 * 16 * KSTRIDE; i += THREADS)
        (&rB[0][0][0])[i] = 0;       // r(x0)=0; k>=100 stays 0 forever

    // ---- J B-fragments (verified layout: col=lane&15, k=(lane>>4)*8+j) ----
    int4 BH[KT], BL[KT];
#pragma unroll
    for (int t = 0; t < KT; ++t) {
        unsigned hs[8], ls[8];
#pragma unroll
        for (int j = 0; j < 8; ++j) {
            int k = 32 * t + 8 * lg + j;
            float v = (hval && k < HID) ? J_w[(size_t)hc * HID + k] : 0.0f;
            bsplit(v, hs[j], ls[j]);
        }
        BH[t] = make_int4((int)(hs[0] | (hs[1] << 16)), (int)(hs[2] | (hs[3] << 16)),
                          (int)(hs[4] | (hs[5] << 16)), (int)(hs[6] | (hs[7] << 16)));
        BL[t] = make_int4((int)(ls[0] | (ls[1] << 16)), (int)(ls[2] | (ls[3] << 16)),
                          (int)(ls[4] | (ls[5] << 16)), (int)(ls[6] | (ls[7] << 16)));
    }
#define PINV(q) asm volatile("" : "+v"(q.x), "+v"(q.y), "+v"(q.z), "+v"(q.w));
    PINV(BH[0]) PINV(BH[1]) PINV(BH[2]) PINV(BH[3])
    PINV(BL[0]) PINV(BL[1]) PINV(BL[2]) PINV(BL[3])
#undef PINV

    const float4 binp = *reinterpret_cast<const float4*>(b_in + (size_t)hc * 4);
    const float  cx   = c_x[hc];

    // x state: batch rows m = 4*lg + i (C layout: row=(lane>>4)*4+reg)
    f32x4 xv = {0.f, 0.f, 0.f, 0.f};

    const size_t bbase = (size_t)bid * 16;

    // ---- 2-deep input prefetch (t=0, t=1) ----
    float4 uP0[4], uP1[4];
    float  nP0[4], nP1[4];
#pragma unroll
    for (int i = 0; i < 4; ++i) {
        const size_t b_i = bbase + 4 * lg + i;
        nP0[i] = noise[((size_t)0 * BATCH + b_i) * HID + hc];
        nP1[i] = noise[((size_t)1 * BATCH + b_i) * HID + hc];
        uP0[i] = *reinterpret_cast<const float4*>(input_seq + ((size_t)0 * BATCH + b_i) * 4);
        uP1[i] = *reinterpret_cast<const float4*>(input_seq + ((size_t)1 * BATCH + b_i) * 4);
    }

    __syncthreads();   // LDS zero-init visible

    for (int t = 0; t < TSTEPS; ++t) {
        const int cur = t & 1, nxt = cur ^ 1;

        // 1. issue prefetch for t+2 (consumed 2 steps later; raw barrier
        //    below does NOT drain vmcnt, so these overlap ~2 full steps)
        const int tn = (t + 2 < TSTEPS) ? (t + 2) : (TSTEPS - 1);
        float4 uP2[4];
        float  nP2[4];
#pragma unroll
        for (int i = 0; i < 4; ++i) {
            const size_t b_i = bbase + 4 * lg + i;
            nP2[i] = noise[((size_t)tn * BATCH + b_i) * HID + hc];
            uP2[i] = *reinterpret_cast<const float4*>(input_seq + ((size_t)tn * BATCH + b_i) * 4);
        }

        // 2. A-fragments of r from LDS (verified: row=lane&15, k=(lane>>4)*8+j)
        bf16x8 ar[KT];
#pragma unroll
        for (int kt = 0; kt < KT; ++kt)
            ar[kt] = *reinterpret_cast<const bf16x8*>(&rB[cur][lr][(4 * kt + lg) * 8]);

        // 3. e[i] = u.b_in + cx + NSTD*nz from landed prefetch regs
        //    (independent VALU; overlaps ds_read latency)
        float e[4];
#pragma unroll
        for (int i = 0; i < 4; ++i)
            e[i] = uP0[i].x * binp.x + uP0[i].y * binp.y + uP0[i].z * binp.z
                 + uP0[i].w * binp.w + cx + NSTD * nP0[i];

        // 4. MFMA: dot = r @ (Jhi + Jlo), two independent chains of 4
        f32x4 aA = {0.f, 0.f, 0.f, 0.f}, aB = aA;
#pragma unroll
        for (int kt = 0; kt < KT; ++kt) {
            aA = __builtin_amdgcn_mfma_f32_16x16x32_bf16(
                     ar[kt], __builtin_bit_cast(bf16x8, BH[kt]), aA, 0, 0, 0);
            aB = __builtin_amdgcn_mfma_f32_16x16x32_bf16(
                     ar[kt], __builtin_bit_cast(bf16x8, BL[kt]), aB, 0, 0, 0);
        }
        f32x4 dot = aA + aB;

        // 5. state update, states store, r_{t+1} pack+write
#pragma unroll
        for (int i = 0; i < 4; ++i) {
            float pre = dot[i] + e[i];
            float xn  = xv[i] + ALPHA * (pre - xv[i]);
            xv[i] = xn;
            if (hval) {
                const size_t b_i = bbase + 4 * lg + i;
                states[((size_t)t * BATCH + b_i) * HID + h] = xn;
                __hip_bfloat16 rb = __float2bfloat16(ftanh(xn));
                rB[nxt][4 * lg + i][h] = *reinterpret_cast<unsigned short*>(&rb);
            }
        }

        // 6. rotate prefetch registers
#pragma unroll
        for (int i = 0; i < 4; ++i) {
            uP0[i] = uP1[i]; uP1[i] = uP2[i];
            nP0[i] = nP1[i]; nP1[i] = nP2[i];
        }

        // 7. raw barrier: drain LDS only; global loads/stores stay in flight
        asm volatile("s_waitcnt lgkmcnt(0)" ::: "memory");
        __builtin_amdgcn_s_barrier();
        __builtin_amdgcn_sched_barrier(0);
    }
}

// Readout: out[b,0] = tanh(states[0,b,:]).wout + wb ; out[b,1] = same at T-1.
__global__ __launch_bounds__(64) void rnn_out_kernel(
    const float* __restrict__ states,
    const float* __restrict__ wout_w,
    const float* __restrict__ wout_b,
    float* __restrict__ out)
{
    const int b = blockIdx.x;
    const int l = threadIdx.x;
    const float* s0 = states + (size_t)b * HID;
    const float* sF = states + ((size_t)(TSTEPS - 1) * BATCH + b) * HID;

    float p0 = 0.f, pF = 0.f;
    if (l < HID) {
        p0 = ftanh(s0[l]) * wout_w[l];
        pF = ftanh(sF[l]) * wout_w[l];
    }
    const int l2 = l + 64;
    if (l2 < HID) {
        p0 += ftanh(s0[l2]) * wout_w[l2];
        pF += ftanh(sF[l2]) * wout_w[l2];
    }
#pragma unroll
    for (int off = 32; off > 0; off >>= 1) {
        p0 += __shfl_xor(p0, off, 64);
        pF += __shfl_xor(pF, off, 64);
    }
    if (l == 0) {
        const float wb = wout_b[0];
        out[b * 2 + 0] = p0 + wb;
        out[b * 2 + 1] = pF + wb;
    }
}

extern "C" void kernel_launch(void* const* d_in, const int* in_sizes, int n_in,
                              void* d_out, int out_size, void* d_ws, size_t ws_size,
                              hipStream_t stream) {
    const float* input_seq = (const float*)d_in[0];
    const float* noise     = (const float*)d_in[1];
    const float* J_w       = (const float*)d_in[2];
    const float* b_in      = (const float*)d_in[3];
    const float* c_x       = (const float*)d_in[4];
    const float* wout_w    = (const float*)d_in[5];
    const float* wout_b    = (const float*)d_in[6];

    float* out    = (float*)d_out;       // [B,2]
    float* states = out + 2 * BATCH;     // [T,B,H]

    rnn_mfma_kernel<<<BATCH / 16, THREADS, 0, stream>>>(
        input_seq, noise, J_w, b_in, c_x, states);
    rnn_out_kernel<<<BATCH, 64, 0, stream>>>(states, wout_w, wout_b, out);
}